// Round 23
// baseline (75.861 us; speedup 1.0000x reference)
//
#include <hip/hip_runtime.h>
#include <hip/hip_bf16.h>
#include <stdint.h>

#define NROW 10000
#define DIM 128
#define NP 10240          // rows padded to 640 tiles of 16
#define KSEL 15
#define JC 32             // j-chunks; cells per row = JC*4 = 128
#define NTILES (NP / 16)  // 640
#define TPC (NTILES / JC) // 20

typedef __attribute__((ext_vector_type(4))) float f32x4;
typedef __attribute__((ext_vector_type(8))) short s16x8;
using bf16_t = __hip_bfloat16;

#define GLD16(gsrc, ldst)                                                          \
    __builtin_amdgcn_global_load_lds(                                              \
        (const __attribute__((address_space(1))) void*)(gsrc),                     \
        (__attribute__((address_space(3))) void*)(ldst), 16, 0, 0)

// ---------------------------------------------------------------- convert
// One wave per row. Writes X in MFMA-fragment-packed layout; sqh = 1024-0.5*|x|^2
// (MFMA C-in). Pad rows: zero data, sqh=1.0 -> key ~1.0, never beats real (~900+).
__global__ __launch_bounds__(256)
void knn_convert(const float* __restrict__ x0, const float* __restrict__ x1,
                 bf16_t* __restrict__ xp, float* __restrict__ sqh,
                 unsigned* __restrict__ counter)
{
    if (blockIdx.x == 0 && threadIdx.x == 0) *counter = 0u;
    const int rg   = blockIdx.x * 4 + (threadIdx.x >> 6);
    const int lane = threadIdx.x & 63;
    if (rg >= 2 * NP) return;
    const int m = rg >= NP ? 1 : 0;
    const int r = rg - m * NP;
    const float* src = m ? x1 : x0;

    float2 v = make_float2(0.f, 0.f);
    float  s = 0.f;
    if (r < NROW) {
        v = *(const float2*)(src + (size_t)r * DIM + lane * 2);
        s = v.x * v.x + v.y * v.y;
    }
    const uint32_t pk = (uint32_t)__bfloat16_as_ushort(__float2bfloat16(v.x))
                      | ((uint32_t)__bfloat16_as_ushort(__float2bfloat16(v.y)) << 16);
    const int e   = lane * 2;
    const int kk  = e >> 5;
    const int gg  = (e >> 3) & 3;
    const int pos = e & 7;
    const size_t off = ((((size_t)m * NTILES + (r >> 4)) * 4 + kk) * 64
                        + (size_t)(gg * 16 + (r & 15))) * 8 + pos;   // even
    *(uint32_t*)(xp + off) = pk;
    #pragma unroll
    for (int o = 32; o; o >>= 1) s += __shfl_down(s, o);
    if (lane == 0) sqh[m * NP + r] = (r < NROW) ? fmaf(s, -0.5f, 1024.0f) : 1.0f;
}

// ---------------------------------------------------------------- main
// ROUND-23 CHANGE (T3+T4 from the guide): COUNTED-vmcnt pipeline. 4 LDS tile
// buffers, stage depth 3; per iter: s_waitcnt vmcnt(2) (own oldest stage
// landed, 2 newer stages stay IN FLIGHT) -> raw s_barrier -> issue stage t+3
// -> compute tile t. This removes the per-tile full vmcnt(0) drain that the
// __syncthreads() versions forced (rounds 18-22 all measured ~= MFMA content
// + LDS content + VALU content, i.e. serialized by the drain; 4 structural
// nulls eliminated barrier-interval / instr-order / occupancy theories).
// Buffer safety: iter t overwrites tile t-1's buffer; its reads were consumed
// (lgkmcnt drained before MFMA use) before any wave passes iter t's barrier.
#define PACKMAX(acc, idxb, Q)                                                     \
    do {                                                                          \
        const uint32_t k0_ = (__float_as_uint((acc)[0]) & 0xFFFFFC00u) | (idxb);  \
        const uint32_t k1_ = (__float_as_uint((acc)[1]) & 0xFFFFFC00u) | ((idxb) | 1u); \
        const uint32_t k2_ = (__float_as_uint((acc)[2]) & 0xFFFFFC00u) | ((idxb) | 2u); \
        const uint32_t k3_ = (__float_as_uint((acc)[3]) & 0xFFFFFC00u) | ((idxb) | 3u); \
        asm("v_max3_u32 %0, %1, %2, %0" : "+v"(Q) : "v"(k0_), "v"(k1_));          \
        asm("v_max3_u32 %0, %1, %2, %0" : "+v"(Q) : "v"(k2_), "v"(k3_));          \
    } while (0)

#define MFMA4(d, set, cin)                                                        \
    f32x4 d = __builtin_amdgcn_mfma_f32_16x16x32_bf16(a0, bfr##set[0], cin, 0, 0, 0); \
    d = __builtin_amdgcn_mfma_f32_16x16x32_bf16(a1, bfr##set[1], d, 0, 0, 0);     \
    d = __builtin_amdgcn_mfma_f32_16x16x32_bf16(a2, bfr##set[2], d, 0, 0, 0);     \
    d = __builtin_amdgcn_mfma_f32_16x16x32_bf16(a3, bfr##set[3], d, 0, 0, 0)

__global__ __launch_bounds__(256, 3)
void knn_topk(const bf16_t* __restrict__ xp, const float* __restrict__ sqh,
              uint32_t* __restrict__ pk2, uint16_t* __restrict__ px2)
{
    __shared__ bf16_t Abuf[4][2048];   // 4 x 4KB tile ring buffer
    __shared__ float  Sbuf[512];       // chunk sq (TPC*16=320 used; padded)

    const int m     = blockIdx.z;
    const int chunk = blockIdx.y;
    const int ib    = blockIdx.x * 256;
    const int wave  = threadIdx.x >> 6;
    const int lane  = threadIdx.x & 63;
    const int li    = lane & 15;
    const int g     = lane >> 4;
    const int tid   = threadIdx.x;

    const bf16_t* XP = xp + (size_t)m * NP * DIM;
    const float*  SQ = sqh + m * NP;

    const int t0 = chunk * TPC;
    const bf16_t* XC = XP + (size_t)t0 * 2048;
    const float*  SC = SQ + t0 * 16;

    // B fragments for four i-sets FIRST (older than all GLD16s -> vmcnt(2)
    // at iter 0 also guarantees these are complete).
    const int ti0 = (ib >> 4) + wave * 4;
    s16x8 bfr0[4], bfr1[4], bfr2[4], bfr3[4];
    #pragma unroll
    for (int kk = 0; kk < 4; ++kk) {
        const size_t bo = ((size_t)kk * 64 + (size_t)(g * 16 + li)) * 8;
        bfr0[kk] = *(const s16x8*)(XP + (size_t)ti0 * 2048 + bo);
        bfr1[kk] = *(const s16x8*)(XP + (size_t)(ti0 + 1) * 2048 + bo);
        bfr2[kk] = *(const s16x8*)(XP + (size_t)(ti0 + 2) * 2048 + bo);
        bfr3[kk] = *(const s16x8*)(XP + (size_t)(ti0 + 3) * 2048 + bo);
    }

    // Stage sq chunk (waves 0,1) and tiles 0,1,2 into buffers 0,1,2.
    if (wave < 2)
        GLD16(SC + (size_t)(wave * 64 + lane) * 4, &Sbuf[wave * 256]);
    GLD16(XC + (size_t)tid * 8, &Abuf[0][wave * 512]);
    GLD16(XC + 2048 + (size_t)tid * 8, &Abuf[1][wave * 512]);
    GLD16(XC + 2 * 2048 + (size_t)tid * 8, &Abuf[2][wave * 512]);

    uint32_t q0 = 0, q1 = 0, q2 = 0, q3 = 0;   // cell max per i-set

    const bf16_t* pf = XC + 3 * 2048 + (size_t)tid * 8;   // staging src (tile t+3)

    for (int t = 0; t < TPC; ++t) {
        // Counted wait: own oldest stage (tile t's part) landed; 2 newer stages
        // stay in flight. Then raw barrier (no compiler vmcnt(0) drain).
        asm volatile("s_waitcnt vmcnt(2)" ::: "memory");
        __builtin_amdgcn_s_barrier();
        asm volatile("" ::: "memory");   // pin: no LDS reads hoisted above

        // Issue stage of tile t+3 into the buffer of (consumed) tile t-1.
        GLD16(pf, &Abuf[(t + 3) & 3][wave * 512]);
        pf += 2048;

        const bf16_t* ab = &Abuf[t & 3][lane * 8];
        const s16x8 a0 = *(const s16x8*)(ab);
        const s16x8 a1 = *(const s16x8*)(ab + 512);
        const s16x8 a2 = *(const s16x8*)(ab + 1024);
        const s16x8 a3 = *(const s16x8*)(ab + 1536);
        const f32x4 sv = *(const f32x4*)&Sbuf[t * 16 + g * 4];

        MFMA4(acc0, 0, sv);
        MFMA4(acc1, 1, sv);
        MFMA4(acc2, 2, sv);
        MFMA4(acc3, 3, sv);

        const uint32_t ib4 = (uint32_t)(t << 2);
        PACKMAX(acc0, ib4, q0);
        PACKMAX(acc1, ib4, q1);
        PACKMAX(acc2, ib4, q2);
        PACKMAX(acc3, ib4, q3);
    }

    // Store cell max + reconstructed j. Plane = (m*JC+chunk)*4 + g, index i.
    const size_t base = ((size_t)((m * JC + chunk) * 4 + g)) * NP;
    #pragma unroll
    for (int s = 0; s < 4; ++s) {
        const uint32_t q = (s == 0) ? q0 : (s == 1) ? q1 : (s == 2) ? q2 : q3;
        const uint32_t id = q & 1023u;
        const int j = (t0 + (int)(id >> 2)) * 16 + g * 4 + (int)(id & 3u);
        const int i = ib + wave * 64 + s * 16 + li;
        pk2[base + i] = q;
        px2[base + i] = (uint16_t)j;
    }
}

// ---------------------------------------------------------------- select stage 1
// One thread per (row, m, half): 64 cell maxes into REGISTER ARRAYS (all loads
// independent & in flight). med3-chain top-15, threshold-rescan, write the 15
// survivors (unsorted) compactly.
#define INS(k, hi, lo) asm("v_med3_u32 %0, %1, %2, %0" : "+v"(lo) : "v"(k), "v"(hi))

__global__ __launch_bounds__(256, 1)
void knn_select_half(const uint32_t* __restrict__ pk2, const uint16_t* __restrict__ px2,
                     uint32_t* __restrict__ sk, uint16_t* __restrict__ sx)
{
    const int i = blockIdx.x * 256 + threadIdx.x;   // row
    const int m = blockIdx.y;
    const int h = blockIdx.z;
    if (i >= NROW) return;

    const uint32_t* pv = pk2 + ((size_t)(m * 128 + h * 64)) * NP + i;
    const uint16_t* px = px2 + ((size_t)(m * 128 + h * 64)) * NP + i;

    uint32_t k[64]; uint16_t jx[64];
    #pragma unroll
    for (int c = 0; c < 64; ++c) {
        k[c]  = pv[(size_t)c * NP];
        jx[c] = px[(size_t)c * NP];
    }
    uint32_t q0 = 0, q1 = 0, q2 = 0, q3 = 0, q4 = 0, q5 = 0, q6 = 0, q7 = 0,
             q8 = 0, q9 = 0, q10 = 0, q11 = 0, q12 = 0, q13 = 0, q14 = 0;
    #pragma unroll
    for (int c = 0; c < 64; ++c) {
        const uint32_t kc = k[c];
        INS(kc, q13, q14); INS(kc, q12, q13); INS(kc, q11, q12); INS(kc, q10, q11);
        INS(kc, q9,  q10); INS(kc, q8,  q9);  INS(kc, q7,  q8);  INS(kc, q6,  q7);
        INS(kc, q5,  q6);  INS(kc, q4,  q5);  INS(kc, q3,  q4);  INS(kc, q2,  q3);
        INS(kc, q1,  q2);  INS(kc, q0,  q1);
        q0 = (q0 > kc) ? q0 : kc;
    }
    const uint32_t thr = q14;
    uint32_t* ok = sk + ((size_t)(m * 2 + h) * KSEL) * NROW + i;
    uint16_t* ox = sx + ((size_t)(m * 2 + h) * KSEL) * NROW + i;
    int n = 0;
    #pragma unroll
    for (int c = 0; c < 64; ++c) {
        if (k[c] >= thr && n < KSEL) {
            ok[(size_t)n * NROW] = k[c];
            ox[(size_t)n * NROW] = jx[c];
            n++;
        }
    }
}

// ---------------------------------------------------------------- select stage 2
// Per (row, m): 30 independent coalesced loads (static indexing), med3-chain
// over 30 -> thr, rescan -> 15 ids into LDS; even threads count the 15x15
// intersection with their odd partner.
__global__ __launch_bounds__(256, 1)
void knn_merge_count(const uint32_t* __restrict__ sk, const uint16_t* __restrict__ sx,
                     unsigned* __restrict__ counter)
{
    __shared__ uint16_t ids[256][KSEL + 3];   // 36B row stride -> bank-shifted
    __shared__ int wsum[4];
    const int tid  = blockIdx.x * 256 + threadIdx.x;
    const int m    = tid & 1;
    const int i    = tid >> 1;
    const int lane = threadIdx.x & 63;
    const int wave = threadIdx.x >> 6;

    if (i < NROW) {
        const uint32_t* pv = sk + (size_t)(m * 2 * KSEL) * NROW + i;
        const uint16_t* px = sx + (size_t)(m * 2 * KSEL) * NROW + i;
        uint32_t k[2 * KSEL]; uint16_t jx[2 * KSEL];
        #pragma unroll
        for (int c = 0; c < 2 * KSEL; ++c) {
            k[c]  = pv[(size_t)c * NROW];
            jx[c] = px[(size_t)c * NROW];
        }
        uint32_t q0 = 0, q1 = 0, q2 = 0, q3 = 0, q4 = 0, q5 = 0, q6 = 0, q7 = 0,
                 q8 = 0, q9 = 0, q10 = 0, q11 = 0, q12 = 0, q13 = 0, q14 = 0;
        #pragma unroll
        for (int c = 0; c < 2 * KSEL; ++c) {
            const uint32_t kc = k[c];
            INS(kc, q13, q14); INS(kc, q12, q13); INS(kc, q11, q12); INS(kc, q10, q11);
            INS(kc, q9,  q10); INS(kc, q8,  q9);  INS(kc, q7,  q8);  INS(kc, q6,  q7);
            INS(kc, q5,  q6);  INS(kc, q4,  q5);  INS(kc, q3,  q4);  INS(kc, q2,  q3);
            INS(kc, q1,  q2);  INS(kc, q0,  q1);
            q0 = (q0 > kc) ? q0 : kc;
        }
        const uint32_t thr = q14;
        int n = 0;
        #pragma unroll
        for (int c = 0; c < 2 * KSEL; ++c) {
            if (k[c] >= thr && n < KSEL) { ids[threadIdx.x][n] = jx[c]; n++; }
        }
    }
    __syncthreads();

    int cnt = 0;
    if (i < NROW && m == 0) {
        #pragma unroll
        for (int a = 0; a < KSEL; ++a) {
            const uint16_t x = ids[threadIdx.x][a];
            #pragma unroll
            for (int b = 0; b < KSEL; ++b)
                cnt += (x == ids[threadIdx.x + 1][b]) ? 1 : 0;
        }
    }
    #pragma unroll
    for (int off = 32; off; off >>= 1) cnt += __shfl_down(cnt, off);
    if (lane == 0) wsum[wave] = cnt;
    __syncthreads();
    if (threadIdx.x == 0)
        atomicAdd(counter, (unsigned)(wsum[0] + wsum[1] + wsum[2] + wsum[3]));
}

__global__ void knn_finalize(const unsigned* __restrict__ counter, float* __restrict__ out)
{
    out[0] = 1.0f - (float)(*counter) / (float)(NROW * KSEL);
}

// ---------------------------------------------------------------- launch
#define XPAD (4 * 2048)   // staging overrun pad (elements; >= 3 tiles needed)
#define SQPAD 512         // sq staging overrun pad (floats)

extern "C" void kernel_launch(void* const* d_in, const int* in_sizes, int n_in,
                              void* d_out, int out_size, void* d_ws, size_t ws_size,
                              hipStream_t stream)
{
    (void)in_sizes; (void)n_in; (void)out_size; (void)ws_size;
    const float* x0 = (const float*)d_in[0];
    const float* x1 = (const float*)d_in[1];
    float* out = (float*)d_out;

    char* ws = (char*)d_ws;
    size_t off = 0;
    bf16_t* xp  = (bf16_t*)(ws + off); off += ((size_t)2 * NP * DIM + XPAD) * sizeof(bf16_t);
    float*  sqh = (float*)(ws + off);  off += ((size_t)2 * NP + SQPAD) * sizeof(float);
    off = (off + 255) & ~(size_t)255;
    uint32_t* pk2 = (uint32_t*)(ws + off); off += (size_t)2 * JC * 4 * NP * sizeof(uint32_t); // 10.5 MB
    uint16_t* px2 = (uint16_t*)(ws + off); off += (size_t)2 * JC * 4 * NP * sizeof(uint16_t); // 5.2 MB
    off = (off + 255) & ~(size_t)255;
    uint32_t* sk = (uint32_t*)(ws + off); off += (size_t)4 * KSEL * NROW * sizeof(uint32_t);  // 2.4 MB
    uint16_t* sx = (uint16_t*)(ws + off); off += (size_t)4 * KSEL * NROW * sizeof(uint16_t);  // 1.2 MB
    off = (off + 255) & ~(size_t)255;
    unsigned* counter = (unsigned*)(ws + off);

    knn_convert<<<(2 * NP) / 4, 256, 0, stream>>>(x0, x1, xp, sqh, counter);
    knn_topk<<<dim3(NP / 256, JC, 2), 256, 0, stream>>>(xp, sqh, pk2, px2);
    knn_select_half<<<dim3((NROW + 255) / 256, 2, 2), 256, 0, stream>>>(pk2, px2, sk, sx);
    knn_merge_count<<<(2 * NROW + 255) / 256, 256, 0, stream>>>(sk, sx, counter);
    knn_finalize<<<1, 1, 0, stream>>>(counter, out);
}

// Round 24
// 73.778 us; speedup vs baseline: 1.0282x; 1.0282x over previous
//
#include <hip/hip_runtime.h>
#include <hip/hip_bf16.h>
#include <stdint.h>

#define NROW 10000
#define DIM 128
#define NP 10240          // rows padded to 640 tiles of 16
#define KSEL 15
#define JC 32             // j-chunks; cells per row = JC*4 = 128
#define NTILES (NP / 16)  // 640
#define TPC (NTILES / JC) // 20 (even)

typedef __attribute__((ext_vector_type(4))) float f32x4;
typedef __attribute__((ext_vector_type(8))) short s16x8;
using bf16_t = __hip_bfloat16;

#define GLD16(gsrc, ldst)                                                          \
    __builtin_amdgcn_global_load_lds(                                              \
        (const __attribute__((address_space(1))) void*)(gsrc),                     \
        (__attribute__((address_space(3))) void*)(ldst), 16, 0, 0)

// ---------------------------------------------------------------- convert
// One wave per row. Writes X in MFMA-fragment-packed layout; sqh = 1024-0.5*|x|^2
// (MFMA C-in). Pad rows: zero data, sqh=1.0 -> key ~1.0, never beats real (~900+).
__global__ __launch_bounds__(256)
void knn_convert(const float* __restrict__ x0, const float* __restrict__ x1,
                 bf16_t* __restrict__ xp, float* __restrict__ sqh,
                 unsigned* __restrict__ counter)
{
    if (blockIdx.x == 0 && threadIdx.x == 0) *counter = 0u;
    const int rg   = blockIdx.x * 4 + (threadIdx.x >> 6);
    const int lane = threadIdx.x & 63;
    if (rg >= 2 * NP) return;
    const int m = rg >= NP ? 1 : 0;
    const int r = rg - m * NP;
    const float* src = m ? x1 : x0;

    float2 v = make_float2(0.f, 0.f);
    float  s = 0.f;
    if (r < NROW) {
        v = *(const float2*)(src + (size_t)r * DIM + lane * 2);
        s = v.x * v.x + v.y * v.y;
    }
    const uint32_t pk = (uint32_t)__bfloat16_as_ushort(__float2bfloat16(v.x))
                      | ((uint32_t)__bfloat16_as_ushort(__float2bfloat16(v.y)) << 16);
    const int e   = lane * 2;
    const int kk  = e >> 5;
    const int gg  = (e >> 3) & 3;
    const int pos = e & 7;
    const size_t off = ((((size_t)m * NTILES + (r >> 4)) * 4 + kk) * 64
                        + (size_t)(gg * 16 + (r & 15))) * 8 + pos;   // even
    *(uint32_t*)(xp + off) = pk;
    #pragma unroll
    for (int o = 32; o; o >>= 1) s += __shfl_down(s, o);
    if (lane == 0) sqh[m * NP + r] = (r < NROW) ? fmaf(s, -0.5f, 1024.0f) : 1.0f;
}

// ---------------------------------------------------------------- main
// ROUND-24 CHANGE: cross-iteration REGISTER PREFETCH of the LDS A-frags.
// Tile t's MFMAs consume regs loaded in iteration t-1; tile t+1's ds_reads
// issue after the END-of-iter barrier -> a full iteration (~300+cyc) between
// ds_read issue and MFMA use, so LDS latency is never exposed (all 6 prior
// structures read LDS immediately before the MFMAs, in block-lockstep bursts).
// Ring of 4 LDS buffers, counted vmcnt(2) (stages stay in flight), raw
// s_barrier. Safety: wave B's reads of buf[t-1] are lgkm-drained before B's
// MFMAs in iter t-1 < barrier(t-1) < wave A's overwriting stage in iter t.
#define PACKMAX(acc, idxb, Q)                                                     \
    do {                                                                          \
        const uint32_t k0_ = (__float_as_uint((acc)[0]) & 0xFFFFFC00u) | (idxb);  \
        const uint32_t k1_ = (__float_as_uint((acc)[1]) & 0xFFFFFC00u) | ((idxb) | 1u); \
        const uint32_t k2_ = (__float_as_uint((acc)[2]) & 0xFFFFFC00u) | ((idxb) | 2u); \
        const uint32_t k3_ = (__float_as_uint((acc)[3]) & 0xFFFFFC00u) | ((idxb) | 3u); \
        asm("v_max3_u32 %0, %1, %2, %0" : "+v"(Q) : "v"(k0_), "v"(k1_));          \
        asm("v_max3_u32 %0, %1, %2, %0" : "+v"(Q) : "v"(k2_), "v"(k3_));          \
    } while (0)

#define MFMA4S(d, A0, A1, A2, A3, set, cin)                                       \
    f32x4 d = __builtin_amdgcn_mfma_f32_16x16x32_bf16(A0, bfr##set[0], cin, 0, 0, 0); \
    d = __builtin_amdgcn_mfma_f32_16x16x32_bf16(A1, bfr##set[1], d, 0, 0, 0);     \
    d = __builtin_amdgcn_mfma_f32_16x16x32_bf16(A2, bfr##set[2], d, 0, 0, 0);     \
    d = __builtin_amdgcn_mfma_f32_16x16x32_bf16(A3, bfr##set[3], d, 0, 0, 0)

// body for tile t: compute from C-set regs, then (after barrier) load tile t+1
// into N-set regs.
#define BODY(t, C0, C1, C2, C3, svC, N0, N1, N2, N3, svN)                         \
    do {                                                                          \
        MFMA4S(acc0, C0, C1, C2, C3, 0, svC);                                     \
        MFMA4S(acc1, C0, C1, C2, C3, 1, svC);                                     \
        MFMA4S(acc2, C0, C1, C2, C3, 2, svC);                                     \
        MFMA4S(acc3, C0, C1, C2, C3, 3, svC);                                     \
        GLD16(pf, &Abuf[((t) + 3) & 3][wave * 512]);                              \
        pf += 2048;                                                               \
        const uint32_t ib4_ = (uint32_t)((t) << 2);                               \
        PACKMAX(acc0, ib4_, q0);                                                  \
        PACKMAX(acc1, ib4_, q1);                                                  \
        PACKMAX(acc2, ib4_, q2);                                                  \
        PACKMAX(acc3, ib4_, q3);                                                  \
        asm volatile("s_waitcnt vmcnt(2)" ::: "memory");                          \
        __builtin_amdgcn_s_barrier();                                             \
        asm volatile("" ::: "memory");                                            \
        const bf16_t* nb_ = &Abuf[((t) + 1) & 3][lane * 8];                       \
        N0 = *(const s16x8*)(nb_);                                                \
        N1 = *(const s16x8*)(nb_ + 512);                                          \
        N2 = *(const s16x8*)(nb_ + 1024);                                         \
        N3 = *(const s16x8*)(nb_ + 1536);                                         \
        svN = *(const f32x4*)&Sbuf[((t) + 1) * 16 + g * 4];                       \
    } while (0)

__global__ __launch_bounds__(256, 3)
void knn_topk(const bf16_t* __restrict__ xp, const float* __restrict__ sqh,
              uint32_t* __restrict__ pk2, uint16_t* __restrict__ px2)
{
    __shared__ bf16_t Abuf[4][2048];   // 4 x 4KB tile ring buffer
    __shared__ float  Sbuf[1024];      // chunk sq (TPC*16+16=336 used; padded 4KB)

    const int m     = blockIdx.z;
    const int chunk = blockIdx.y;
    const int ib    = blockIdx.x * 256;
    const int wave  = threadIdx.x >> 6;
    const int lane  = threadIdx.x & 63;
    const int li    = lane & 15;
    const int g     = lane >> 4;
    const int tid   = threadIdx.x;

    const bf16_t* XP = xp + (size_t)m * NP * DIM;
    const float*  SQ = sqh + m * NP;

    const int t0 = chunk * TPC;
    const bf16_t* XC = XP + (size_t)t0 * 2048;
    const float*  SC = SQ + t0 * 16;

    // B fragments FIRST (oldest vmcnt entries -> drained by the pre-loop wait).
    const int ti0 = (ib >> 4) + wave * 4;
    s16x8 bfr0[4], bfr1[4], bfr2[4], bfr3[4];
    #pragma unroll
    for (int kk = 0; kk < 4; ++kk) {
        const size_t bo = ((size_t)kk * 64 + (size_t)(g * 16 + li)) * 8;
        bfr0[kk] = *(const s16x8*)(XP + (size_t)ti0 * 2048 + bo);
        bfr1[kk] = *(const s16x8*)(XP + (size_t)(ti0 + 1) * 2048 + bo);
        bfr2[kk] = *(const s16x8*)(XP + (size_t)(ti0 + 2) * 2048 + bo);
        bfr3[kk] = *(const s16x8*)(XP + (size_t)(ti0 + 3) * 2048 + bo);
    }

    // Stage sq chunk (ALL 4 waves, 1KB each -> uniform per-wave vmcnt counts)
    // and tiles 0,1,2 into ring buffers 0,1,2.
    GLD16(SC + (size_t)tid * 4, &Sbuf[wave * 256]);
    GLD16(XC + (size_t)tid * 8, &Abuf[0][wave * 512]);
    GLD16(XC + 2048 + (size_t)tid * 8, &Abuf[1][wave * 512]);
    GLD16(XC + 2 * 2048 + (size_t)tid * 8, &Abuf[2][wave * 512]);

    uint32_t q0 = 0, q1 = 0, q2 = 0, q3 = 0;   // cell max per i-set

    const bf16_t* pf = XC + 3 * 2048 + (size_t)tid * 8;   // staging src (tile t+3)

    // Pre-loop: stage0 + bfr + sq landed (all but 2 newest = stages 1,2).
    asm volatile("s_waitcnt vmcnt(2)" ::: "memory");
    __builtin_amdgcn_s_barrier();
    asm volatile("" ::: "memory");

    // Load tile 0 into the A register set.
    s16x8 aA0, aA1, aA2, aA3, aB0, aB1, aB2, aB3;
    f32x4 svA, svB;
    {
        const bf16_t* ab = &Abuf[0][lane * 8];
        aA0 = *(const s16x8*)(ab);
        aA1 = *(const s16x8*)(ab + 512);
        aA2 = *(const s16x8*)(ab + 1024);
        aA3 = *(const s16x8*)(ab + 1536);
        svA = *(const f32x4*)&Sbuf[g * 4];
    }

    for (int p = 0; p < TPC / 2; ++p) {
        const int t = 2 * p;
        BODY(t,     aA0, aA1, aA2, aA3, svA, aB0, aB1, aB2, aB3, svB);
        BODY(t + 1, aB0, aB1, aB2, aB3, svB, aA0, aA1, aA2, aA3, svA);
    }

    // Store cell max + reconstructed j. Plane = (m*JC+chunk)*4 + g, index i.
    const size_t base = ((size_t)((m * JC + chunk) * 4 + g)) * NP;
    #pragma unroll
    for (int s = 0; s < 4; ++s) {
        const uint32_t q = (s == 0) ? q0 : (s == 1) ? q1 : (s == 2) ? q2 : q3;
        const uint32_t id = q & 1023u;
        const int j = (t0 + (int)(id >> 2)) * 16 + g * 4 + (int)(id & 3u);
        const int i = ib + wave * 64 + s * 16 + li;
        pk2[base + i] = q;
        px2[base + i] = (uint16_t)j;
    }
}

// ---------------------------------------------------------------- select stage 1
// One thread per (row, m, half): 64 cell maxes into REGISTER ARRAYS (all loads
// independent & in flight). med3-chain top-15, threshold-rescan, write the 15
// survivors (unsorted) compactly.
#define INS(k, hi, lo) asm("v_med3_u32 %0, %1, %2, %0" : "+v"(lo) : "v"(k), "v"(hi))

__global__ __launch_bounds__(256, 1)
void knn_select_half(const uint32_t* __restrict__ pk2, const uint16_t* __restrict__ px2,
                     uint32_t* __restrict__ sk, uint16_t* __restrict__ sx)
{
    const int i = blockIdx.x * 256 + threadIdx.x;   // row
    const int m = blockIdx.y;
    const int h = blockIdx.z;
    if (i >= NROW) return;

    const uint32_t* pv = pk2 + ((size_t)(m * 128 + h * 64)) * NP + i;
    const uint16_t* px = px2 + ((size_t)(m * 128 + h * 64)) * NP + i;

    uint32_t k[64]; uint16_t jx[64];
    #pragma unroll
    for (int c = 0; c < 64; ++c) {
        k[c]  = pv[(size_t)c * NP];
        jx[c] = px[(size_t)c * NP];
    }
    uint32_t q0 = 0, q1 = 0, q2 = 0, q3 = 0, q4 = 0, q5 = 0, q6 = 0, q7 = 0,
             q8 = 0, q9 = 0, q10 = 0, q11 = 0, q12 = 0, q13 = 0, q14 = 0;
    #pragma unroll
    for (int c = 0; c < 64; ++c) {
        const uint32_t kc = k[c];
        INS(kc, q13, q14); INS(kc, q12, q13); INS(kc, q11, q12); INS(kc, q10, q11);
        INS(kc, q9,  q10); INS(kc, q8,  q9);  INS(kc, q7,  q8);  INS(kc, q6,  q7);
        INS(kc, q5,  q6);  INS(kc, q4,  q5);  INS(kc, q3,  q4);  INS(kc, q2,  q3);
        INS(kc, q1,  q2);  INS(kc, q0,  q1);
        q0 = (q0 > kc) ? q0 : kc;
    }
    const uint32_t thr = q14;
    uint32_t* ok = sk + ((size_t)(m * 2 + h) * KSEL) * NROW + i;
    uint16_t* ox = sx + ((size_t)(m * 2 + h) * KSEL) * NROW + i;
    int n = 0;
    #pragma unroll
    for (int c = 0; c < 64; ++c) {
        if (k[c] >= thr && n < KSEL) {
            ok[(size_t)n * NROW] = k[c];
            ox[(size_t)n * NROW] = jx[c];
            n++;
        }
    }
}

// ---------------------------------------------------------------- select stage 2
// Per (row, m): 30 independent coalesced loads (static indexing), med3-chain
// over 30 -> thr, rescan -> 15 ids into LDS; even threads count the 15x15
// intersection with their odd partner.
__global__ __launch_bounds__(256, 1)
void knn_merge_count(const uint32_t* __restrict__ sk, const uint16_t* __restrict__ sx,
                     unsigned* __restrict__ counter)
{
    __shared__ uint16_t ids[256][KSEL + 3];   // 36B row stride -> bank-shifted
    __shared__ int wsum[4];
    const int tid  = blockIdx.x * 256 + threadIdx.x;
    const int m    = tid & 1;
    const int i    = tid >> 1;
    const int lane = threadIdx.x & 63;
    const int wave = threadIdx.x >> 6;

    if (i < NROW) {
        const uint32_t* pv = sk + (size_t)(m * 2 * KSEL) * NROW + i;
        const uint16_t* px = sx + (size_t)(m * 2 * KSEL) * NROW + i;
        uint32_t k[2 * KSEL]; uint16_t jx[2 * KSEL];
        #pragma unroll
        for (int c = 0; c < 2 * KSEL; ++c) {
            k[c]  = pv[(size_t)c * NROW];
            jx[c] = px[(size_t)c * NROW];
        }
        uint32_t q0 = 0, q1 = 0, q2 = 0, q3 = 0, q4 = 0, q5 = 0, q6 = 0, q7 = 0,
                 q8 = 0, q9 = 0, q10 = 0, q11 = 0, q12 = 0, q13 = 0, q14 = 0;
        #pragma unroll
        for (int c = 0; c < 2 * KSEL; ++c) {
            const uint32_t kc = k[c];
            INS(kc, q13, q14); INS(kc, q12, q13); INS(kc, q11, q12); INS(kc, q10, q11);
            INS(kc, q9,  q10); INS(kc, q8,  q9);  INS(kc, q7,  q8);  INS(kc, q6,  q7);
            INS(kc, q5,  q6);  INS(kc, q4,  q5);  INS(kc, q3,  q4);  INS(kc, q2,  q3);
            INS(kc, q1,  q2);  INS(kc, q0,  q1);
            q0 = (q0 > kc) ? q0 : kc;
        }
        const uint32_t thr = q14;
        int n = 0;
        #pragma unroll
        for (int c = 0; c < 2 * KSEL; ++c) {
            if (k[c] >= thr && n < KSEL) { ids[threadIdx.x][n] = jx[c]; n++; }
        }
    }
    __syncthreads();

    int cnt = 0;
    if (i < NROW && m == 0) {
        #pragma unroll
        for (int a = 0; a < KSEL; ++a) {
            const uint16_t x = ids[threadIdx.x][a];
            #pragma unroll
            for (int b = 0; b < KSEL; ++b)
                cnt += (x == ids[threadIdx.x + 1][b]) ? 1 : 0;
        }
    }
    #pragma unroll
    for (int off = 32; off; off >>= 1) cnt += __shfl_down(cnt, off);
    if (lane == 0) wsum[wave] = cnt;
    __syncthreads();
    if (threadIdx.x == 0)
        atomicAdd(counter, (unsigned)(wsum[0] + wsum[1] + wsum[2] + wsum[3]));
}

__global__ void knn_finalize(const unsigned* __restrict__ counter, float* __restrict__ out)
{
    out[0] = 1.0f - (float)(*counter) / (float)(NROW * KSEL);
}

// ---------------------------------------------------------------- launch
#define XPAD (4 * 2048)   // staging overrun pad (elements; >= 3 tiles needed)
#define SQPAD 1024        // sq staging overrun pad (floats)

extern "C" void kernel_launch(void* const* d_in, const int* in_sizes, int n_in,
                              void* d_out, int out_size, void* d_ws, size_t ws_size,
                              hipStream_t stream)
{
    (void)in_sizes; (void)n_in; (void)out_size; (void)ws_size;
    const float* x0 = (const float*)d_in[0];
    const float* x1 = (const float*)d_in[1];
    float* out = (float*)d_out;

    char* ws = (char*)d_ws;
    size_t off = 0;
    bf16_t* xp  = (bf16_t*)(ws + off); off += ((size_t)2 * NP * DIM + XPAD) * sizeof(bf16_t);
    float*  sqh = (float*)(ws + off);  off += ((size_t)2 * NP + SQPAD) * sizeof(float);
    off = (off + 255) & ~(size_t)255;
    uint32_t* pk2 = (uint32_t*)(ws + off); off += (size_t)2 * JC * 4 * NP * sizeof(uint32_t); // 10.5 MB
    uint16_t* px2 = (uint16_t*)(ws + off); off += (size_t)2 * JC * 4 * NP * sizeof(uint16_t); // 5.2 MB
    off = (off + 255) & ~(size_t)255;
    uint32_t* sk = (uint32_t*)(ws + off); off += (size_t)4 * KSEL * NROW * sizeof(uint32_t);  // 2.4 MB
    uint16_t* sx = (uint16_t*)(ws + off); off += (size_t)4 * KSEL * NROW * sizeof(uint16_t);  // 1.2 MB
    off = (off + 255) & ~(size_t)255;
    unsigned* counter = (unsigned*)(ws + off);

    knn_convert<<<(2 * NP) / 4, 256, 0, stream>>>(x0, x1, xp, sqh, counter);
    knn_topk<<<dim3(NP / 256, JC, 2), 256, 0, stream>>>(xp, sqh, pk2, px2);
    knn_select_half<<<dim3((NROW + 255) / 256, 2, 2), 256, 0, stream>>>(pk2, px2, sk, sx);
    knn_merge_count<<<(2 * NROW + 255) / 256, 256, 0, stream>>>(sk, sx, counter);
    knn_finalize<<<1, 1, 0, stream>>>(counter, out);
}

// Round 25
// 68.459 us; speedup vs baseline: 1.1081x; 1.0777x over previous
//
#include <hip/hip_runtime.h>
#include <hip/hip_bf16.h>
#include <stdint.h>

#define NROW 10000
#define DIM 128
#define NP 10240          // rows padded to 640 tiles of 16
#define KSEL 15
#define JC 32             // j-chunks; cells per row = JC*4 = 128
#define NTILES (NP / 16)  // 640
#define TPC (NTILES / JC) // 20

typedef __attribute__((ext_vector_type(4))) float f32x4;
typedef __attribute__((ext_vector_type(8))) short s16x8;
using bf16_t = __hip_bfloat16;

#define GLD16(gsrc, ldst)                                                          \
    __builtin_amdgcn_global_load_lds(                                              \
        (const __attribute__((address_space(1))) void*)(gsrc),                     \
        (__attribute__((address_space(3))) void*)(ldst), 16, 0, 0)

// ---------------------------------------------------------------- convert
// One wave per row. Writes X in MFMA-fragment-packed layout; sqh = 1024-0.5*|x|^2
// (MFMA C-in). Pad rows: zero data, sqh=1.0 -> key ~1.0, never beats real (~900+).
__global__ __launch_bounds__(256)
void knn_convert(const float* __restrict__ x0, const float* __restrict__ x1,
                 bf16_t* __restrict__ xp, float* __restrict__ sqh,
                 unsigned* __restrict__ counter, unsigned* __restrict__ done)
{
    if (blockIdx.x == 0 && threadIdx.x == 0) { *counter = 0u; *done = 0u; }
    const int rg   = blockIdx.x * 4 + (threadIdx.x >> 6);
    const int lane = threadIdx.x & 63;
    if (rg >= 2 * NP) return;
    const int m = rg >= NP ? 1 : 0;
    const int r = rg - m * NP;
    const float* src = m ? x1 : x0;

    float2 v = make_float2(0.f, 0.f);
    float  s = 0.f;
    if (r < NROW) {
        v = *(const float2*)(src + (size_t)r * DIM + lane * 2);
        s = v.x * v.x + v.y * v.y;
    }
    const uint32_t pk = (uint32_t)__bfloat16_as_ushort(__float2bfloat16(v.x))
                      | ((uint32_t)__bfloat16_as_ushort(__float2bfloat16(v.y)) << 16);
    const int e   = lane * 2;
    const int kk  = e >> 5;
    const int gg  = (e >> 3) & 3;
    const int pos = e & 7;
    const size_t off = ((((size_t)m * NTILES + (r >> 4)) * 4 + kk) * 64
                        + (size_t)(gg * 16 + (r & 15))) * 8 + pos;   // even
    *(uint32_t*)(xp + off) = pk;
    #pragma unroll
    for (int o = 32; o; o >>= 1) s += __shfl_down(s, o);
    if (lane == 0) sqh[m * NP + r] = (r < NROW) ? fmaf(s, -0.5f, 1024.0f) : 1.0f;
}

// ---------------------------------------------------------------- main
// ROUND-19 VARIANT RESTORED (best measured: 46.3us). Six structural rewrites
// (barrier interval, instr order, occupancy 2.5x, counted vmcnt, reg prefetch)
// were all null: topk time ~= partially-overlapped SUM of MFMA+VALU+LDS issue
// content, insensitive to source-level scheduling. LDS-staged A-stream, one
// tile per barrier, double buffer. Key = dot + 1024 - 0.5*sq[j] (MFMA C-in),
// 22-bit key + 10-bit chunk-local index. LCAP=1 cell max per (i,chunk,group).
#define PACKMAX(acc, idxb, Q)                                                     \
    do {                                                                          \
        const uint32_t k0_ = (__float_as_uint((acc)[0]) & 0xFFFFFC00u) | (idxb);  \
        const uint32_t k1_ = (__float_as_uint((acc)[1]) & 0xFFFFFC00u) | ((idxb) | 1u); \
        const uint32_t k2_ = (__float_as_uint((acc)[2]) & 0xFFFFFC00u) | ((idxb) | 2u); \
        const uint32_t k3_ = (__float_as_uint((acc)[3]) & 0xFFFFFC00u) | ((idxb) | 3u); \
        asm("v_max3_u32 %0, %1, %2, %0" : "+v"(Q) : "v"(k0_), "v"(k1_));          \
        asm("v_max3_u32 %0, %1, %2, %0" : "+v"(Q) : "v"(k2_), "v"(k3_));          \
    } while (0)

#define MFMA4(d, set, cin)                                                        \
    f32x4 d = __builtin_amdgcn_mfma_f32_16x16x32_bf16(a0, bfr##set[0], cin, 0, 0, 0); \
    d = __builtin_amdgcn_mfma_f32_16x16x32_bf16(a1, bfr##set[1], d, 0, 0, 0);     \
    d = __builtin_amdgcn_mfma_f32_16x16x32_bf16(a2, bfr##set[2], d, 0, 0, 0);     \
    d = __builtin_amdgcn_mfma_f32_16x16x32_bf16(a3, bfr##set[3], d, 0, 0, 0)

__global__ __launch_bounds__(256, 3)
void knn_topk(const bf16_t* __restrict__ xp, const float* __restrict__ sqh,
              uint32_t* __restrict__ pk2, uint16_t* __restrict__ px2)
{
    __shared__ bf16_t Abuf[2][2048];   // 2 x 4KB j-tile double buffer
    __shared__ float  Sbuf[512];       // chunk sq (TPC*16=320 used; padded)

    const int m     = blockIdx.z;
    const int chunk = blockIdx.y;
    const int ib    = blockIdx.x * 256;
    const int wave  = threadIdx.x >> 6;
    const int lane  = threadIdx.x & 63;
    const int li    = lane & 15;
    const int g     = lane >> 4;
    const int tid   = threadIdx.x;

    const bf16_t* XP = xp + (size_t)m * NP * DIM;
    const float*  SQ = sqh + m * NP;

    const int t0 = chunk * TPC;
    const bf16_t* XC = XP + (size_t)t0 * 2048;
    const float*  SC = SQ + t0 * 16;

    // Stage sq chunk (waves 0,1: 2KB) and A-tile 0; barrier at loop top drains.
    if (wave < 2)
        GLD16(SC + (size_t)(wave * 64 + lane) * 4, &Sbuf[wave * 256]);
    GLD16(XC + (size_t)tid * 8, &Abuf[0][wave * 512]);

    // B fragments for four i-sets (persistent; normal global loads).
    const int ti0 = (ib >> 4) + wave * 4;
    s16x8 bfr0[4], bfr1[4], bfr2[4], bfr3[4];
    #pragma unroll
    for (int kk = 0; kk < 4; ++kk) {
        const size_t bo = ((size_t)kk * 64 + (size_t)(g * 16 + li)) * 8;
        bfr0[kk] = *(const s16x8*)(XP + (size_t)ti0 * 2048 + bo);
        bfr1[kk] = *(const s16x8*)(XP + (size_t)(ti0 + 1) * 2048 + bo);
        bfr2[kk] = *(const s16x8*)(XP + (size_t)(ti0 + 2) * 2048 + bo);
        bfr3[kk] = *(const s16x8*)(XP + (size_t)(ti0 + 3) * 2048 + bo);
    }

    uint32_t q0 = 0, q1 = 0, q2 = 0, q3 = 0;   // cell max per i-set

    const bf16_t* pf = XC + 2048 + (size_t)tid * 8;   // staging src for tile t+1

    for (int t = 0; t < TPC; ++t) {
        __syncthreads();   // buf[t&1] staged (iter t-1) & prior reads of buf[(t+1)&1] done

        const bf16_t* ab = &Abuf[t & 1][lane * 8];
        const s16x8 a0 = *(const s16x8*)(ab);
        const s16x8 a1 = *(const s16x8*)(ab + 512);
        const s16x8 a2 = *(const s16x8*)(ab + 1024);
        const s16x8 a3 = *(const s16x8*)(ab + 1536);
        const f32x4 sv = *(const f32x4*)&Sbuf[t * 16 + g * 4];

        // Stage tile t+1 (lands during this tile's MFMAs; overrun reads pad).
        GLD16(pf, &Abuf[(t + 1) & 1][wave * 512]);
        pf += 2048;

        MFMA4(acc0, 0, sv);
        MFMA4(acc1, 1, sv);
        MFMA4(acc2, 2, sv);
        MFMA4(acc3, 3, sv);

        const uint32_t ib4 = (uint32_t)(t << 2);
        PACKMAX(acc0, ib4, q0);
        PACKMAX(acc1, ib4, q1);
        PACKMAX(acc2, ib4, q2);
        PACKMAX(acc3, ib4, q3);
    }

    // Store cell max + reconstructed j. Plane = (m*JC+chunk)*4 + g, index i.
    const size_t base = ((size_t)((m * JC + chunk) * 4 + g)) * NP;
    #pragma unroll
    for (int s = 0; s < 4; ++s) {
        const uint32_t q = (s == 0) ? q0 : (s == 1) ? q1 : (s == 2) ? q2 : q3;
        const uint32_t id = q & 1023u;
        const int j = (t0 + (int)(id >> 2)) * 16 + g * 4 + (int)(id & 3u);
        const int i = ib + wave * 64 + s * 16 + li;
        pk2[base + i] = q;
        px2[base + i] = (uint16_t)j;
    }
}

// ---------------------------------------------------------------- fused select + count + finalize
// One block per 64 rows (157 blocks). Stage 1 (all 256 thr): plane (m,h) =
// (t>>7, (t>>6)&1), row = t&63 -> 64 consecutive i per wave (fully coalesced
// loads); 64 cell maxes into REGISTER ARRAYS (proven no-spill pattern),
// med3-chain top-15, threshold-rescan -> 15 (key,id) into LDS. Stage 2
// (t<128): merge own row's two halves (30 LDS candidates) -> 15 ids. Stage 3
// (t<64): 15x15 intersection m0 x m1, wave-reduce, one atomicAdd. Finalize
// via device-scope done-ticket (fence + atomic read) -- no extra launch.
#define INS(k, hi, lo) asm("v_med3_u32 %0, %1, %2, %0" : "+v"(lo) : "v"(k), "v"(hi))

#define CHAIN15(kc)                                                               \
    do {                                                                          \
        INS(kc, q13, q14); INS(kc, q12, q13); INS(kc, q11, q12); INS(kc, q10, q11); \
        INS(kc, q9,  q10); INS(kc, q8,  q9);  INS(kc, q7,  q8);  INS(kc, q6,  q7); \
        INS(kc, q5,  q6);  INS(kc, q4,  q5);  INS(kc, q3,  q4);  INS(kc, q2,  q3); \
        INS(kc, q1,  q2);  INS(kc, q0,  q1);                                      \
        q0 = (q0 > (kc)) ? q0 : (kc);                                             \
    } while (0)

__global__ __launch_bounds__(256, 1)
void knn_select_count(const uint32_t* __restrict__ pk2, const uint16_t* __restrict__ px2,
                      unsigned* __restrict__ counter, unsigned* __restrict__ done,
                      float* __restrict__ out)
{
    __shared__ uint32_t lv1[64][2][2][KSEL + 1];  // stage-1 keys  (33 KB)
    __shared__ uint16_t lx1[64][2][2][KSEL + 1];  // stage-1 ids   (16.5 KB)
    __shared__ uint16_t idsF[64][2][KSEL + 1];    // stage-2 ids   (4 KB)

    const int t    = threadIdx.x;
    const int row  = t & 63;
    const int i    = blockIdx.x * 64 + row;
    const int h    = (t >> 6) & 1;
    const int m    = t >> 7;

    // ---- stage 1: per (row, m, h): top-15 of 64 cell maxes ----
    if (i < NROW) {
        const uint32_t* pv = pk2 + ((size_t)(m * 128 + h * 64)) * NP + i;
        const uint16_t* px = px2 + ((size_t)(m * 128 + h * 64)) * NP + i;
        uint32_t k[64]; uint16_t jx[64];
        #pragma unroll
        for (int c = 0; c < 64; ++c) {
            k[c]  = pv[(size_t)c * NP];
            jx[c] = px[(size_t)c * NP];
        }
        uint32_t q0 = 0, q1 = 0, q2 = 0, q3 = 0, q4 = 0, q5 = 0, q6 = 0, q7 = 0,
                 q8 = 0, q9 = 0, q10 = 0, q11 = 0, q12 = 0, q13 = 0, q14 = 0;
        #pragma unroll
        for (int c = 0; c < 64; ++c) { const uint32_t kc = k[c]; CHAIN15(kc); }
        const uint32_t thr = q14;
        int n = 0;
        #pragma unroll
        for (int c = 0; c < 64; ++c) {
            if (k[c] >= thr && n < KSEL) {
                lv1[row][m][h][n] = k[c];
                lx1[row][m][h][n] = jx[c];
                n++;
            }
        }
    }
    __syncthreads();

    // ---- stage 2: per (row, m): top-15 of the two halves' 30 ----
    if (t < 128 && i < NROW) {
        const int mm = h;   // reuse bit: threads 0..63 -> m=0, 64..127 -> m=1
        uint32_t k[2 * KSEL]; uint16_t jx[2 * KSEL];
        #pragma unroll
        for (int c = 0; c < KSEL; ++c) {
            k[c]           = lv1[row][mm][0][c];
            jx[c]          = lx1[row][mm][0][c];
            k[KSEL + c]    = lv1[row][mm][1][c];
            jx[KSEL + c]   = lx1[row][mm][1][c];
        }
        uint32_t q0 = 0, q1 = 0, q2 = 0, q3 = 0, q4 = 0, q5 = 0, q6 = 0, q7 = 0,
                 q8 = 0, q9 = 0, q10 = 0, q11 = 0, q12 = 0, q13 = 0, q14 = 0;
        #pragma unroll
        for (int c = 0; c < 2 * KSEL; ++c) { const uint32_t kc = k[c]; CHAIN15(kc); }
        const uint32_t thr = q14;
        int n = 0;
        #pragma unroll
        for (int c = 0; c < 2 * KSEL; ++c) {
            if (k[c] >= thr && n < KSEL) { idsF[row][mm][n] = jx[c]; n++; }
        }
    }
    __syncthreads();

    // ---- stage 3: per row: 15x15 intersection; wave-0 reduce; atomic ----
    int cnt = 0;
    if (t < 64 && i < NROW) {
        #pragma unroll
        for (int a = 0; a < KSEL; ++a) {
            const uint16_t x = idsF[row][0][a];
            #pragma unroll
            for (int b = 0; b < KSEL; ++b)
                cnt += (x == idsF[row][1][b]) ? 1 : 0;
        }
    }
    if (t < 64) {
        #pragma unroll
        for (int o = 32; o; o >>= 1) cnt += __shfl_down(cnt, o);
        if (t == 0) {
            atomicAdd(counter, (unsigned)cnt);
            __threadfence();
            const unsigned prev = atomicAdd(done, 1u);
            if (prev == gridDim.x - 1) {
                const unsigned total = atomicAdd(counter, 0u);
                out[0] = 1.0f - (float)total / (float)(NROW * KSEL);
            }
        }
    }
}

// ---------------------------------------------------------------- launch
#define XPAD (4 * 2048)   // staging overrun pad (elements)
#define SQPAD 512         // sq staging overrun pad (floats)

extern "C" void kernel_launch(void* const* d_in, const int* in_sizes, int n_in,
                              void* d_out, int out_size, void* d_ws, size_t ws_size,
                              hipStream_t stream)
{
    (void)in_sizes; (void)n_in; (void)out_size; (void)ws_size;
    const float* x0 = (const float*)d_in[0];
    const float* x1 = (const float*)d_in[1];
    float* out = (float*)d_out;

    char* ws = (char*)d_ws;
    size_t off = 0;
    bf16_t* xp  = (bf16_t*)(ws + off); off += ((size_t)2 * NP * DIM + XPAD) * sizeof(bf16_t);
    float*  sqh = (float*)(ws + off);  off += ((size_t)2 * NP + SQPAD) * sizeof(float);
    off = (off + 255) & ~(size_t)255;
    uint32_t* pk2 = (uint32_t*)(ws + off); off += (size_t)2 * JC * 4 * NP * sizeof(uint32_t); // 10.5 MB
    uint16_t* px2 = (uint16_t*)(ws + off); off += (size_t)2 * JC * 4 * NP * sizeof(uint16_t); // 5.2 MB
    off = (off + 255) & ~(size_t)255;
    unsigned* counter = (unsigned*)(ws + off); off += 256;
    unsigned* done    = (unsigned*)(ws + off);

    knn_convert<<<(2 * NP) / 4, 256, 0, stream>>>(x0, x1, xp, sqh, counter, done);
    knn_topk<<<dim3(NP / 256, JC, 2), 256, 0, stream>>>(xp, sqh, pk2, px2);
    knn_select_count<<<(NROW + 63) / 64, 256, 0, stream>>>(pk2, px2, counter, done, out);
}

// Round 26
// 68.010 us; speedup vs baseline: 1.1154x; 1.0066x over previous
//
#include <hip/hip_runtime.h>
#include <hip/hip_bf16.h>
#include <stdint.h>

#define NROW 10000
#define DIM 128
#define NP 10240          // rows padded to 640 tiles of 16
#define KSEL 15
#define JC 32             // j-chunks; cells per row = JC*4 = 128
#define NTILES (NP / 16)  // 640
#define TPC (NTILES / JC) // 20

typedef __attribute__((ext_vector_type(4))) float f32x4;
typedef __attribute__((ext_vector_type(8))) short s16x8;
using bf16_t = __hip_bfloat16;

#define GLD16(gsrc, ldst)                                                          \
    __builtin_amdgcn_global_load_lds(                                              \
        (const __attribute__((address_space(1))) void*)(gsrc),                     \
        (__attribute__((address_space(3))) void*)(ldst), 16, 0, 0)

// ---------------------------------------------------------------- convert
// One wave per row. Writes X in MFMA-fragment-packed layout; sqh = 1024-0.5*|x|^2
// (MFMA C-in). Pad rows: zero data, sqh=1.0 -> key ~1.0, never beats real (~900+).
__global__ __launch_bounds__(256)
void knn_convert(const float* __restrict__ x0, const float* __restrict__ x1,
                 bf16_t* __restrict__ xp, float* __restrict__ sqh,
                 unsigned* __restrict__ counter, unsigned* __restrict__ done)
{
    if (blockIdx.x == 0 && threadIdx.x == 0) { *counter = 0u; *done = 0u; }
    const int rg   = blockIdx.x * 4 + (threadIdx.x >> 6);
    const int lane = threadIdx.x & 63;
    if (rg >= 2 * NP) return;
    const int m = rg >= NP ? 1 : 0;
    const int r = rg - m * NP;
    const float* src = m ? x1 : x0;

    float2 v = make_float2(0.f, 0.f);
    float  s = 0.f;
    if (r < NROW) {
        v = *(const float2*)(src + (size_t)r * DIM + lane * 2);
        s = v.x * v.x + v.y * v.y;
    }
    const uint32_t pk = (uint32_t)__bfloat16_as_ushort(__float2bfloat16(v.x))
                      | ((uint32_t)__bfloat16_as_ushort(__float2bfloat16(v.y)) << 16);
    const int e   = lane * 2;
    const int kk  = e >> 5;
    const int gg  = (e >> 3) & 3;
    const int pos = e & 7;
    const size_t off = ((((size_t)m * NTILES + (r >> 4)) * 4 + kk) * 64
                        + (size_t)(gg * 16 + (r & 15))) * 8 + pos;   // even
    *(uint32_t*)(xp + off) = pk;
    #pragma unroll
    for (int o = 32; o; o >>= 1) s += __shfl_down(s, o);
    if (lane == 0) sqh[m * NP + r] = (r < NROW) ? fmaf(s, -0.5f, 1024.0f) : 1.0f;
}

// ---------------------------------------------------------------- main
// ROUND-19 VARIANT (best measured: 46.2us; six structural rewrites were null —
// topk time ~= partially-overlapped SUM of MFMA+VALU+LDS issue content).
// LDS-staged A-stream, one tile per barrier, double buffer. Key = dot + 1024 -
// 0.5*sq[j] (MFMA C-in), 22-bit key + 10-bit chunk-local index. LCAP=1 cell max.
#define PACKMAX(acc, idxb, Q)                                                     \
    do {                                                                          \
        const uint32_t k0_ = (__float_as_uint((acc)[0]) & 0xFFFFFC00u) | (idxb);  \
        const uint32_t k1_ = (__float_as_uint((acc)[1]) & 0xFFFFFC00u) | ((idxb) | 1u); \
        const uint32_t k2_ = (__float_as_uint((acc)[2]) & 0xFFFFFC00u) | ((idxb) | 2u); \
        const uint32_t k3_ = (__float_as_uint((acc)[3]) & 0xFFFFFC00u) | ((idxb) | 3u); \
        asm("v_max3_u32 %0, %1, %2, %0" : "+v"(Q) : "v"(k0_), "v"(k1_));          \
        asm("v_max3_u32 %0, %1, %2, %0" : "+v"(Q) : "v"(k2_), "v"(k3_));          \
    } while (0)

#define MFMA4(d, set, cin)                                                        \
    f32x4 d = __builtin_amdgcn_mfma_f32_16x16x32_bf16(a0, bfr##set[0], cin, 0, 0, 0); \
    d = __builtin_amdgcn_mfma_f32_16x16x32_bf16(a1, bfr##set[1], d, 0, 0, 0);     \
    d = __builtin_amdgcn_mfma_f32_16x16x32_bf16(a2, bfr##set[2], d, 0, 0, 0);     \
    d = __builtin_amdgcn_mfma_f32_16x16x32_bf16(a3, bfr##set[3], d, 0, 0, 0)

__global__ __launch_bounds__(256, 3)
void knn_topk(const bf16_t* __restrict__ xp, const float* __restrict__ sqh,
              uint32_t* __restrict__ pk2, uint16_t* __restrict__ px2)
{
    __shared__ bf16_t Abuf[2][2048];   // 2 x 4KB j-tile double buffer
    __shared__ float  Sbuf[512];       // chunk sq (TPC*16=320 used; padded)

    const int m     = blockIdx.z;
    const int chunk = blockIdx.y;
    const int ib    = blockIdx.x * 256;
    const int wave  = threadIdx.x >> 6;
    const int lane  = threadIdx.x & 63;
    const int li    = lane & 15;
    const int g     = lane >> 4;
    const int tid   = threadIdx.x;

    const bf16_t* XP = xp + (size_t)m * NP * DIM;
    const float*  SQ = sqh + m * NP;

    const int t0 = chunk * TPC;
    const bf16_t* XC = XP + (size_t)t0 * 2048;
    const float*  SC = SQ + t0 * 16;

    if (wave < 2)
        GLD16(SC + (size_t)(wave * 64 + lane) * 4, &Sbuf[wave * 256]);
    GLD16(XC + (size_t)tid * 8, &Abuf[0][wave * 512]);

    const int ti0 = (ib >> 4) + wave * 4;
    s16x8 bfr0[4], bfr1[4], bfr2[4], bfr3[4];
    #pragma unroll
    for (int kk = 0; kk < 4; ++kk) {
        const size_t bo = ((size_t)kk * 64 + (size_t)(g * 16 + li)) * 8;
        bfr0[kk] = *(const s16x8*)(XP + (size_t)ti0 * 2048 + bo);
        bfr1[kk] = *(const s16x8*)(XP + (size_t)(ti0 + 1) * 2048 + bo);
        bfr2[kk] = *(const s16x8*)(XP + (size_t)(ti0 + 2) * 2048 + bo);
        bfr3[kk] = *(const s16x8*)(XP + (size_t)(ti0 + 3) * 2048 + bo);
    }

    uint32_t q0 = 0, q1 = 0, q2 = 0, q3 = 0;   // cell max per i-set

    const bf16_t* pf = XC + 2048 + (size_t)tid * 8;   // staging src for tile t+1

    for (int t = 0; t < TPC; ++t) {
        __syncthreads();

        const bf16_t* ab = &Abuf[t & 1][lane * 8];
        const s16x8 a0 = *(const s16x8*)(ab);
        const s16x8 a1 = *(const s16x8*)(ab + 512);
        const s16x8 a2 = *(const s16x8*)(ab + 1024);
        const s16x8 a3 = *(const s16x8*)(ab + 1536);
        const f32x4 sv = *(const f32x4*)&Sbuf[t * 16 + g * 4];

        GLD16(pf, &Abuf[(t + 1) & 1][wave * 512]);
        pf += 2048;

        MFMA4(acc0, 0, sv);
        MFMA4(acc1, 1, sv);
        MFMA4(acc2, 2, sv);
        MFMA4(acc3, 3, sv);

        const uint32_t ib4 = (uint32_t)(t << 2);
        PACKMAX(acc0, ib4, q0);
        PACKMAX(acc1, ib4, q1);
        PACKMAX(acc2, ib4, q2);
        PACKMAX(acc3, ib4, q3);
    }

    const size_t base = ((size_t)((m * JC + chunk) * 4 + g)) * NP;
    #pragma unroll
    for (int s = 0; s < 4; ++s) {
        const uint32_t q = (s == 0) ? q0 : (s == 1) ? q1 : (s == 2) ? q2 : q3;
        const uint32_t id = q & 1023u;
        const int j = (t0 + (int)(id >> 2)) * 16 + g * 4 + (int)(id & 3u);
        const int i = ib + wave * 64 + s * 16 + li;
        pk2[base + i] = q;
        px2[base + i] = (uint16_t)j;
    }
}

// ---------------------------------------------------------------- fused select + count + finalize
// ROUND-26 CHANGE: LDS layouts transposed to ODD row strides. Previous layout
// lv1[64][2][2][16] gave word-addr = row*64 + n -> bank independent of row ->
// all 64 lanes same bank (814K conflicts measured). Now lv1[2][2][64][17]:
// word-addr = row*17 + n -> (row*17)%32 cycles all banks; idsF stride 9 words.
#define INS(k, hi, lo) asm("v_med3_u32 %0, %1, %2, %0" : "+v"(lo) : "v"(k), "v"(hi))

#define CHAIN15(kc)                                                               \
    do {                                                                          \
        INS(kc, q13, q14); INS(kc, q12, q13); INS(kc, q11, q12); INS(kc, q10, q11); \
        INS(kc, q9,  q10); INS(kc, q8,  q9);  INS(kc, q7,  q8);  INS(kc, q6,  q7); \
        INS(kc, q5,  q6);  INS(kc, q4,  q5);  INS(kc, q3,  q4);  INS(kc, q2,  q3); \
        INS(kc, q1,  q2);  INS(kc, q0,  q1);                                      \
        q0 = (q0 > (kc)) ? q0 : (kc);                                             \
    } while (0)

__global__ __launch_bounds__(256, 1)
void knn_select_count(const uint32_t* __restrict__ pk2, const uint16_t* __restrict__ px2,
                      unsigned* __restrict__ counter, unsigned* __restrict__ done,
                      float* __restrict__ out)
{
    __shared__ uint32_t lv1[2][2][64][KSEL + 2];  // 17-word row stride (34.8 KB)
    __shared__ uint16_t lx1[2][2][64][KSEL + 2];  // (17.4 KB)
    __shared__ uint16_t idsF[2][64][KSEL + 3];    // 9-word row stride (4.6 KB)

    const int t    = threadIdx.x;
    const int row  = t & 63;
    const int i    = blockIdx.x * 64 + row;
    const int h    = (t >> 6) & 1;
    const int m    = t >> 7;

    // ---- stage 1: per (row, m, h): top-15 of 64 cell maxes ----
    if (i < NROW) {
        const uint32_t* pv = pk2 + ((size_t)(m * 128 + h * 64)) * NP + i;
        const uint16_t* px = px2 + ((size_t)(m * 128 + h * 64)) * NP + i;
        uint32_t k[64]; uint16_t jx[64];
        #pragma unroll
        for (int c = 0; c < 64; ++c) {
            k[c]  = pv[(size_t)c * NP];
            jx[c] = px[(size_t)c * NP];
        }
        uint32_t q0 = 0, q1 = 0, q2 = 0, q3 = 0, q4 = 0, q5 = 0, q6 = 0, q7 = 0,
                 q8 = 0, q9 = 0, q10 = 0, q11 = 0, q12 = 0, q13 = 0, q14 = 0;
        #pragma unroll
        for (int c = 0; c < 64; ++c) { const uint32_t kc = k[c]; CHAIN15(kc); }
        const uint32_t thr = q14;
        int n = 0;
        #pragma unroll
        for (int c = 0; c < 64; ++c) {
            if (k[c] >= thr && n < KSEL) {
                lv1[m][h][row][n] = k[c];
                lx1[m][h][row][n] = jx[c];
                n++;
            }
        }
    }
    __syncthreads();

    // ---- stage 2: per (row, m): top-15 of the two halves' 30 ----
    if (t < 128 && i < NROW) {
        const int mm = h;   // threads 0..63 -> m=0, 64..127 -> m=1
        uint32_t k[2 * KSEL]; uint16_t jx[2 * KSEL];
        #pragma unroll
        for (int c = 0; c < KSEL; ++c) {
            k[c]         = lv1[mm][0][row][c];
            jx[c]        = lx1[mm][0][row][c];
            k[KSEL + c]  = lv1[mm][1][row][c];
            jx[KSEL + c] = lx1[mm][1][row][c];
        }
        uint32_t q0 = 0, q1 = 0, q2 = 0, q3 = 0, q4 = 0, q5 = 0, q6 = 0, q7 = 0,
                 q8 = 0, q9 = 0, q10 = 0, q11 = 0, q12 = 0, q13 = 0, q14 = 0;
        #pragma unroll
        for (int c = 0; c < 2 * KSEL; ++c) { const uint32_t kc = k[c]; CHAIN15(kc); }
        const uint32_t thr = q14;
        int n = 0;
        #pragma unroll
        for (int c = 0; c < 2 * KSEL; ++c) {
            if (k[c] >= thr && n < KSEL) { idsF[mm][row][n] = jx[c]; n++; }
        }
    }
    __syncthreads();

    // ---- stage 3: per row: 15x15 intersection; wave-0 reduce; atomic ----
    int cnt = 0;
    if (t < 64 && i < NROW) {
        #pragma unroll
        for (int a = 0; a < KSEL; ++a) {
            const uint16_t x = idsF[0][row][a];
            #pragma unroll
            for (int b = 0; b < KSEL; ++b)
                cnt += (x == idsF[1][row][b]) ? 1 : 0;
        }
    }
    if (t < 64) {
        #pragma unroll
        for (int o = 32; o; o >>= 1) cnt += __shfl_down(cnt, o);
        if (t == 0) {
            atomicAdd(counter, (unsigned)cnt);
            __threadfence();
            const unsigned prev = atomicAdd(done, 1u);
            if (prev == gridDim.x - 1) {
                const unsigned total = atomicAdd(counter, 0u);
                out[0] = 1.0f - (float)total / (float)(NROW * KSEL);
            }
        }
    }
}

// ---------------------------------------------------------------- launch
#define XPAD (4 * 2048)   // staging overrun pad (elements)
#define SQPAD 512         // sq staging overrun pad (floats)

extern "C" void kernel_launch(void* const* d_in, const int* in_sizes, int n_in,
                              void* d_out, int out_size, void* d_ws, size_t ws_size,
                              hipStream_t stream)
{
    (void)in_sizes; (void)n_in; (void)out_size; (void)ws_size;
    const float* x0 = (const float*)d_in[0];
    const float* x1 = (const float*)d_in[1];
    float* out = (float*)d_out;

    char* ws = (char*)d_ws;
    size_t off = 0;
    bf16_t* xp  = (bf16_t*)(ws + off); off += ((size_t)2 * NP * DIM + XPAD) * sizeof(bf16_t);
    float*  sqh = (float*)(ws + off);  off += ((size_t)2 * NP + SQPAD) * sizeof(float);
    off = (off + 255) & ~(size_t)255;
    uint32_t* pk2 = (uint32_t*)(ws + off); off += (size_t)2 * JC * 4 * NP * sizeof(uint32_t); // 10.5 MB
    uint16_t* px2 = (uint16_t*)(ws + off); off += (size_t)2 * JC * 4 * NP * sizeof(uint16_t); // 5.2 MB
    off = (off + 255) & ~(size_t)255;
    unsigned* counter = (unsigned*)(ws + off); off += 256;
    unsigned* done    = (unsigned*)(ws + off);

    knn_convert<<<(2 * NP) / 4, 256, 0, stream>>>(x0, x1, xp, sqh, counter, done);
    knn_topk<<<dim3(NP / 256, JC, 2), 256, 0, stream>>>(xp, sqh, pk2, px2);
    knn_select_count<<<(NROW + 63) / 64, 256, 0, stream>>>(pk2, px2, counter, done, out);
}

// Round 27
// 67.420 us; speedup vs baseline: 1.1252x; 1.0087x over previous
//
#include <hip/hip_runtime.h>
#include <hip/hip_bf16.h>
#include <stdint.h>

#define NROW 10000
#define DIM 128
#define NP 10240          // rows padded to 640 tiles of 16
#define KSEL 15
#define JC 32             // j-chunks; cells per row = JC*4 = 128
#define NTILES (NP / 16)  // 640
#define TPC (NTILES / JC) // 20

typedef __attribute__((ext_vector_type(4))) float f32x4;
typedef __attribute__((ext_vector_type(8))) short s16x8;
using bf16_t = __hip_bfloat16;

#define GLD16(gsrc, ldst)                                                          \
    __builtin_amdgcn_global_load_lds(                                              \
        (const __attribute__((address_space(1))) void*)(gsrc),                     \
        (__attribute__((address_space(3))) void*)(ldst), 16, 0, 0)

// ---------------------------------------------------------------- convert
// ROUND-27 REWRITE: tile-coalesced. One block per (tile, m); thread t owns row
// t&15, elements (t>>6)*32+((t>>4)&3)*8..+8 — the 8 consecutive source floats
// whose bf16s land at dst+t*8 (identity: t*8 = kk*512+gg*128+r15*8, the old
// scatter formula). Two 16B reads + ONE 16B fully-coalesced store per thread
// (old version: 4B scattered stores). Row sq via shfl_xor(16,32) + tiny LDS
// cross-wave reduce. Pad rows (tiles >= 625): zeros, sqh = 1.0.
__global__ __launch_bounds__(256)
void knn_convert(const float* __restrict__ x0, const float* __restrict__ x1,
                 bf16_t* __restrict__ xp, float* __restrict__ sqh,
                 unsigned* __restrict__ counter, unsigned* __restrict__ done)
{
    __shared__ float ws[4][16];

    const int tile = blockIdx.x;
    const int m    = blockIdx.y;
    const int t    = threadIdx.x;
    const int lane = t & 63;
    const int wave = t >> 6;
    const int r15  = t & 15;

    if (tile == 0 && m == 0 && t == 0) { *counter = 0u; *done = 0u; }

    const float* src = m ? x1 : x0;
    const int r  = tile * 16 + r15;
    const int eb = (t >> 6) * 32 + ((t >> 4) & 3) * 8;

    f32x4 v0 = {0.f, 0.f, 0.f, 0.f}, v1 = {0.f, 0.f, 0.f, 0.f};
    if (r < NROW) {
        v0 = *(const f32x4*)(src + (size_t)r * DIM + eb);
        v1 = *(const f32x4*)(src + (size_t)r * DIM + eb + 4);
    }

    // pack 8 floats -> 8 bf16 -> one 16B store at dst + t*8
    uint32_t pk[4];
    #pragma unroll
    for (int p = 0; p < 4; ++p) {
        const float lo = (p < 2) ? v0[2 * p]     : v1[2 * p - 4];
        const float hi = (p < 2) ? v0[2 * p + 1] : v1[2 * p - 3];
        pk[p] = (uint32_t)__bfloat16_as_ushort(__float2bfloat16(lo))
              | ((uint32_t)__bfloat16_as_ushort(__float2bfloat16(hi)) << 16);
    }
    bf16_t* dst = xp + (size_t)m * NP * DIM + (size_t)tile * 2048 + (size_t)t * 8;
    *(s16x8*)dst = *(s16x8*)pk;

    // row squared-norm: per-lane partial, reduce over lanes sharing r15
    float s = v0[0]*v0[0] + v0[1]*v0[1] + v0[2]*v0[2] + v0[3]*v0[3]
            + v1[0]*v1[0] + v1[1]*v1[1] + v1[2]*v1[2] + v1[3]*v1[3];
    s += __shfl_xor(s, 16);
    s += __shfl_xor(s, 32);
    if (lane < 16) ws[wave][lane] = s;
    __syncthreads();
    if (t < 16) {
        const float tot = ws[0][t] + ws[1][t] + ws[2][t] + ws[3][t];
        const int rr = tile * 16 + t;
        sqh[m * NP + rr] = (rr < NROW) ? fmaf(tot, -0.5f, 1024.0f) : 1.0f;
    }
}

// ---------------------------------------------------------------- main
// ROUND-19 VARIANT (best measured: 46.2us; six structural rewrites were null —
// topk time ~= partially-overlapped SUM of MFMA+VALU+LDS issue content).
// LDS-staged A-stream, one tile per barrier, double buffer. Key = dot + 1024 -
// 0.5*sq[j] (MFMA C-in), 22-bit key + 10-bit chunk-local index. LCAP=1 cell max.
#define PACKMAX(acc, idxb, Q)                                                     \
    do {                                                                          \
        const uint32_t k0_ = (__float_as_uint((acc)[0]) & 0xFFFFFC00u) | (idxb);  \
        const uint32_t k1_ = (__float_as_uint((acc)[1]) & 0xFFFFFC00u) | ((idxb) | 1u); \
        const uint32_t k2_ = (__float_as_uint((acc)[2]) & 0xFFFFFC00u) | ((idxb) | 2u); \
        const uint32_t k3_ = (__float_as_uint((acc)[3]) & 0xFFFFFC00u) | ((idxb) | 3u); \
        asm("v_max3_u32 %0, %1, %2, %0" : "+v"(Q) : "v"(k0_), "v"(k1_));          \
        asm("v_max3_u32 %0, %1, %2, %0" : "+v"(Q) : "v"(k2_), "v"(k3_));          \
    } while (0)

#define MFMA4(d, set, cin)                                                        \
    f32x4 d = __builtin_amdgcn_mfma_f32_16x16x32_bf16(a0, bfr##set[0], cin, 0, 0, 0); \
    d = __builtin_amdgcn_mfma_f32_16x16x32_bf16(a1, bfr##set[1], d, 0, 0, 0);     \
    d = __builtin_amdgcn_mfma_f32_16x16x32_bf16(a2, bfr##set[2], d, 0, 0, 0);     \
    d = __builtin_amdgcn_mfma_f32_16x16x32_bf16(a3, bfr##set[3], d, 0, 0, 0)

__global__ __launch_bounds__(256, 3)
void knn_topk(const bf16_t* __restrict__ xp, const float* __restrict__ sqh,
              uint32_t* __restrict__ pk2, uint16_t* __restrict__ px2)
{
    __shared__ bf16_t Abuf[2][2048];   // 2 x 4KB j-tile double buffer
    __shared__ float  Sbuf[512];       // chunk sq (TPC*16=320 used; padded)

    const int m     = blockIdx.z;
    const int chunk = blockIdx.y;
    const int ib    = blockIdx.x * 256;
    const int wave  = threadIdx.x >> 6;
    const int lane  = threadIdx.x & 63;
    const int li    = lane & 15;
    const int g     = lane >> 4;
    const int tid   = threadIdx.x;

    const bf16_t* XP = xp + (size_t)m * NP * DIM;
    const float*  SQ = sqh + m * NP;

    const int t0 = chunk * TPC;
    const bf16_t* XC = XP + (size_t)t0 * 2048;
    const float*  SC = SQ + t0 * 16;

    if (wave < 2)
        GLD16(SC + (size_t)(wave * 64 + lane) * 4, &Sbuf[wave * 256]);
    GLD16(XC + (size_t)tid * 8, &Abuf[0][wave * 512]);

    const int ti0 = (ib >> 4) + wave * 4;
    s16x8 bfr0[4], bfr1[4], bfr2[4], bfr3[4];
    #pragma unroll
    for (int kk = 0; kk < 4; ++kk) {
        const size_t bo = ((size_t)kk * 64 + (size_t)(g * 16 + li)) * 8;
        bfr0[kk] = *(const s16x8*)(XP + (size_t)ti0 * 2048 + bo);
        bfr1[kk] = *(const s16x8*)(XP + (size_t)(ti0 + 1) * 2048 + bo);
        bfr2[kk] = *(const s16x8*)(XP + (size_t)(ti0 + 2) * 2048 + bo);
        bfr3[kk] = *(const s16x8*)(XP + (size_t)(ti0 + 3) * 2048 + bo);
    }

    uint32_t q0 = 0, q1 = 0, q2 = 0, q3 = 0;   // cell max per i-set

    const bf16_t* pf = XC + 2048 + (size_t)tid * 8;   // staging src for tile t+1

    for (int t = 0; t < TPC; ++t) {
        __syncthreads();

        const bf16_t* ab = &Abuf[t & 1][lane * 8];
        const s16x8 a0 = *(const s16x8*)(ab);
        const s16x8 a1 = *(const s16x8*)(ab + 512);
        const s16x8 a2 = *(const s16x8*)(ab + 1024);
        const s16x8 a3 = *(const s16x8*)(ab + 1536);
        const f32x4 sv = *(const f32x4*)&Sbuf[t * 16 + g * 4];

        GLD16(pf, &Abuf[(t + 1) & 1][wave * 512]);
        pf += 2048;

        MFMA4(acc0, 0, sv);
        MFMA4(acc1, 1, sv);
        MFMA4(acc2, 2, sv);
        MFMA4(acc3, 3, sv);

        const uint32_t ib4 = (uint32_t)(t << 2);
        PACKMAX(acc0, ib4, q0);
        PACKMAX(acc1, ib4, q1);
        PACKMAX(acc2, ib4, q2);
        PACKMAX(acc3, ib4, q3);
    }

    const size_t base = ((size_t)((m * JC + chunk) * 4 + g)) * NP;
    #pragma unroll
    for (int s = 0; s < 4; ++s) {
        const uint32_t q = (s == 0) ? q0 : (s == 1) ? q1 : (s == 2) ? q2 : q3;
        const uint32_t id = q & 1023u;
        const int j = (t0 + (int)(id >> 2)) * 16 + g * 4 + (int)(id & 3u);
        const int i = ib + wave * 64 + s * 16 + li;
        pk2[base + i] = q;
        px2[base + i] = (uint16_t)j;
    }
}

// ---------------------------------------------------------------- fused select + count + finalize
// Odd-stride LDS (round-26 fix: conflicts 814K -> 90K). Stage 1: top-15 of 64
// cell maxes per (row,m,h) via register arrays; stage 2: merge halves; stage 3:
// 15x15 intersection + done-ticket finalize.
#define INS(k, hi, lo) asm("v_med3_u32 %0, %1, %2, %0" : "+v"(lo) : "v"(k), "v"(hi))

#define CHAIN15(kc)                                                               \
    do {                                                                          \
        INS(kc, q13, q14); INS(kc, q12, q13); INS(kc, q11, q12); INS(kc, q10, q11); \
        INS(kc, q9,  q10); INS(kc, q8,  q9);  INS(kc, q7,  q8);  INS(kc, q6,  q7); \
        INS(kc, q5,  q6);  INS(kc, q4,  q5);  INS(kc, q3,  q4);  INS(kc, q2,  q3); \
        INS(kc, q1,  q2);  INS(kc, q0,  q1);                                      \
        q0 = (q0 > (kc)) ? q0 : (kc);                                             \
    } while (0)

__global__ __launch_bounds__(256, 1)
void knn_select_count(const uint32_t* __restrict__ pk2, const uint16_t* __restrict__ px2,
                      unsigned* __restrict__ counter, unsigned* __restrict__ done,
                      float* __restrict__ out)
{
    __shared__ uint32_t lv1[2][2][64][KSEL + 2];  // 17-word row stride
    __shared__ uint16_t lx1[2][2][64][KSEL + 2];
    __shared__ uint16_t idsF[2][64][KSEL + 3];    // 9-word row stride

    const int t    = threadIdx.x;
    const int row  = t & 63;
    const int i    = blockIdx.x * 64 + row;
    const int h    = (t >> 6) & 1;
    const int m    = t >> 7;

    if (i < NROW) {
        const uint32_t* pv = pk2 + ((size_t)(m * 128 + h * 64)) * NP + i;
        const uint16_t* px = px2 + ((size_t)(m * 128 + h * 64)) * NP + i;
        uint32_t k[64]; uint16_t jx[64];
        #pragma unroll
        for (int c = 0; c < 64; ++c) {
            k[c]  = pv[(size_t)c * NP];
            jx[c] = px[(size_t)c * NP];
        }
        uint32_t q0 = 0, q1 = 0, q2 = 0, q3 = 0, q4 = 0, q5 = 0, q6 = 0, q7 = 0,
                 q8 = 0, q9 = 0, q10 = 0, q11 = 0, q12 = 0, q13 = 0, q14 = 0;
        #pragma unroll
        for (int c = 0; c < 64; ++c) { const uint32_t kc = k[c]; CHAIN15(kc); }
        const uint32_t thr = q14;
        int n = 0;
        #pragma unroll
        for (int c = 0; c < 64; ++c) {
            if (k[c] >= thr && n < KSEL) {
                lv1[m][h][row][n] = k[c];
                lx1[m][h][row][n] = jx[c];
                n++;
            }
        }
    }
    __syncthreads();

    if (t < 128 && i < NROW) {
        const int mm = h;
        uint32_t k[2 * KSEL]; uint16_t jx[2 * KSEL];
        #pragma unroll
        for (int c = 0; c < KSEL; ++c) {
            k[c]         = lv1[mm][0][row][c];
            jx[c]        = lx1[mm][0][row][c];
            k[KSEL + c]  = lv1[mm][1][row][c];
            jx[KSEL + c] = lx1[mm][1][row][c];
        }
        uint32_t q0 = 0, q1 = 0, q2 = 0, q3 = 0, q4 = 0, q5 = 0, q6 = 0, q7 = 0,
                 q8 = 0, q9 = 0, q10 = 0, q11 = 0, q12 = 0, q13 = 0, q14 = 0;
        #pragma unroll
        for (int c = 0; c < 2 * KSEL; ++c) { const uint32_t kc = k[c]; CHAIN15(kc); }
        const uint32_t thr = q14;
        int n = 0;
        #pragma unroll
        for (int c = 0; c < 2 * KSEL; ++c) {
            if (k[c] >= thr && n < KSEL) { idsF[mm][row][n] = jx[c]; n++; }
        }
    }
    __syncthreads();

    int cnt = 0;
    if (t < 64 && i < NROW) {
        #pragma unroll
        for (int a = 0; a < KSEL; ++a) {
            const uint16_t x = idsF[0][row][a];
            #pragma unroll
            for (int b = 0; b < KSEL; ++b)
                cnt += (x == idsF[1][row][b]) ? 1 : 0;
        }
    }
    if (t < 64) {
        #pragma unroll
        for (int o = 32; o; o >>= 1) cnt += __shfl_down(cnt, o);
        if (t == 0) {
            atomicAdd(counter, (unsigned)cnt);
            __threadfence();
            const unsigned prev = atomicAdd(done, 1u);
            if (prev == gridDim.x - 1) {
                const unsigned total = atomicAdd(counter, 0u);
                out[0] = 1.0f - (float)total / (float)(NROW * KSEL);
            }
        }
    }
}

// ---------------------------------------------------------------- launch
#define XPAD (4 * 2048)   // staging overrun pad (elements)
#define SQPAD 512         // sq staging overrun pad (floats)

extern "C" void kernel_launch(void* const* d_in, const int* in_sizes, int n_in,
                              void* d_out, int out_size, void* d_ws, size_t ws_size,
                              hipStream_t stream)
{
    (void)in_sizes; (void)n_in; (void)out_size; (void)ws_size;
    const float* x0 = (const float*)d_in[0];
    const float* x1 = (const float*)d_in[1];
    float* out = (float*)d_out;

    char* ws = (char*)d_ws;
    size_t off = 0;
    bf16_t* xp  = (bf16_t*)(ws + off); off += ((size_t)2 * NP * DIM + XPAD) * sizeof(bf16_t);
    float*  sqh = (float*)(ws + off);  off += ((size_t)2 * NP + SQPAD) * sizeof(float);
    off = (off + 255) & ~(size_t)255;
    uint32_t* pk2 = (uint32_t*)(ws + off); off += (size_t)2 * JC * 4 * NP * sizeof(uint32_t); // 10.5 MB
    uint16_t* px2 = (uint16_t*)(ws + off); off += (size_t)2 * JC * 4 * NP * sizeof(uint16_t); // 5.2 MB
    off = (off + 255) & ~(size_t)255;
    unsigned* counter = (unsigned*)(ws + off); off += 256;
    unsigned* done    = (unsigned*)(ws + off);

    knn_convert<<<dim3(NTILES, 2), 256, 0, stream>>>(x0, x1, xp, sqh, counter, done);
    knn_topk<<<dim3(NP / 256, JC, 2), 256, 0, stream>>>(xp, sqh, pk2, px2);
    knn_select_count<<<(NROW + 63) / 64, 256, 0, stream>>>(pk2, px2, counter, done, out);
}